// Round 8
// baseline (145.127 us; speedup 1.0000x reference)
//
#include <hip/hip_runtime.h>
#include <hip/hip_bf16.h>
#include <stdint.h>

// AttentionHelper: B=8, C=256, L=2048
//   energy[b,l,m] = sum_c Q[b,c,l]*K[b,c,m]
//   A = softmax_m(energy/16 banded; masked -> unnormalized exp = 1e-6)
//   out[b,c,l] = sum_m V[b,c,m]*A[b,l,m]
// k_prep (Q/K fp32->fp16 transpose, vectorized) -> k_energy_exp (QK^T ->
// unnormalized exp fp16 + rowsum partials; masked-tile blocks convert V) ->
// k_fused (inline rinv + normalized fp32 att + PV GEMM; V loaded direct to
// MFMA fragments from L2 — wave-private rows — P-only LDS, double-buffered).
// NO non-temporal stores: vmcnt(0) drain at barriers waits for NT acks (R7:
// +30us regression). b-fastest grids pin each batch's panels to one XCD L2.

namespace {
constexpr int B = 8, C = 256, L = 2048;
constexpr int BAND = L / 2 + 64;   // 1088
constexpr float SCALE = 0.0625f;   // 1/sqrt(256)
}

typedef _Float16 f16x8 __attribute__((ext_vector_type(8)));
typedef _Float16 f16x4 __attribute__((ext_vector_type(4)));
typedef _Float16 f16x2 __attribute__((ext_vector_type(2)));
typedef float f32x4_t __attribute__((ext_vector_type(4)));

__device__ __forceinline__ void gload_lds16(const void* g, void* l) {
  __builtin_amdgcn_global_load_lds((const __attribute__((address_space(1))) void*)g,
                                   (__attribute__((address_space(3))) void*)l,
                                   16, 0, 0);
}

// K0: transpose (C,L)fp32 -> (L,C)fp16 for Q (z<8) / K (z>=8); 64l x 64c tiles.
__global__ __launch_bounds__(256) void k_prep(const float* __restrict__ Q,
                                              const float* __restrict__ K,
                                              _Float16* __restrict__ Qh,
                                              _Float16* __restrict__ Kh) {
  __shared__ float tile[64 * 65];
  const int z = blockIdx.z;
  const float* src = (z < 8) ? Q : K;
  _Float16* dst = (z < 8) ? Qh : Kh;
  const int b = z & 7;
  const int l0 = blockIdx.x * 64, c0 = blockIdx.y * 64;
  const float* s = src + (size_t)b * C * L;
  const int t = threadIdx.x;
#pragma unroll
  for (int i = 0; i < 4; ++i) {
    int idx = i * 256 + t;            // 0..1023
    int c = idx >> 4, q = idx & 15;   // c-row 0..63, l-quad 0..15
    float4 v = *(const float4*)&s[(size_t)(c0 + c) * L + l0 + q * 4];
    tile[c * 65 + q * 4 + 0] = v.x;
    tile[c * 65 + q * 4 + 1] = v.y;
    tile[c * 65 + q * 4 + 2] = v.z;
    tile[c * 65 + q * 4 + 3] = v.w;
  }
  __syncthreads();
  _Float16* d = dst + (size_t)b * L * C;
#pragma unroll
  for (int i = 0; i < 2; ++i) {
    int u = i * 256 + t;              // 0..511
    int cg = u & 7, l = u >> 3;       // 8 lanes cover 128B contiguous
    f16x8 h;
#pragma unroll
    for (int e = 0; e < 8; ++e) h[e] = (_Float16)tile[(cg * 8 + e) * 65 + l];
    *(f16x8*)(d + (size_t)(l0 + l) * C + c0 + cg * 8) = h;
  }
}

// K1: QK^T GEMM (128x128 tile, BK=64, double-buffered prefetch) -> exp ->
//     fp16 att_h + rowsum partials. 1D grid, b fastest (XCD pin).
//     Fully-masked tiles (21/batch) convert V fp32->fp16 instead (grid-stride).
__global__ __launch_bounds__(256) void k_energy_exp(const _Float16* __restrict__ Qh,
                                                    const _Float16* __restrict__ Kh,
                                                    const float* __restrict__ Vf,
                                                    _Float16* __restrict__ Vh,
                                                    _Float16* __restrict__ atth,
                                                    float* __restrict__ partials) {
  const int idx = blockIdx.x;
  const int b = idx & 7, li = (idx >> 3) & 15, mi = idx >> 7;
  const int t = threadIdx.x;
  if (mi >= li + 10) {  // fully-masked tile: do V conversion work instead
    int id = b * 21 + (li * 6 - (li * (li - 1)) / 2) + (mi - li - 10);  // 0..167
    const float4* src = (const float4*)Vf;
    f16x4* dst = (f16x4*)Vh;
    for (int i = id * 256 + t; i < B * C * L / 4; i += 168 * 256) {
      float4 v = src[i];
      f16x4 o = { (_Float16)v.x, (_Float16)v.y, (_Float16)v.z, (_Float16)v.w };
      dst[i] = o;
    }
    return;
  }
  const int m0 = mi * 128, l0 = li * 128;
  __shared__ char smem[66 * 1024];
  const _Float16* Qb = Qh + (size_t)b * L * C;
  const _Float16* Kb = Kh + (size_t)b * L * C;
  const int lane = t & 63, wv = t >> 6;
  const int wr = (wv >> 1) * 64, wc = (wv & 1) * 64;
  const int fr = lane & 15, hi = lane >> 4;
  f32x4_t acc[4][4] = {};

  auto stage = [&](int buf, int k0) {
#pragma unroll
    for (int ss = 0; ss < 4; ++ss) {
      int q = ss * 256 + t;                 // 1024 chunks of 16B per matrix
      int row = q >> 3, seg = q & 7, g = seg ^ (row & 7);
      gload_lds16(Qb + (size_t)(l0 + row) * C + k0 + g * 8,
                  smem + buf * 16384 + q * 16);
      gload_lds16(Kb + (size_t)(m0 + row) * C + k0 + g * 8,
                  smem + 32768 + buf * 16384 + q * 16);
    }
  };

  stage(0, 0);
  __syncthreads();
#pragma unroll
  for (int s = 0; s < 4; ++s) {
    if (s < 3) stage((s + 1) & 1, (s + 1) * 64);
    const char* A = smem + (s & 1) * 16384;
    const char* Bb_ = smem + 32768 + (s & 1) * 16384;
#pragma unroll
    for (int kk = 0; kk < 2; ++kk) {
      f16x8 ar[4], br[4];
      const int g = kk * 4 + hi;
#pragma unroll
      for (int i = 0; i < 4; ++i) {
        int r = wr + i * 16 + fr;
        ar[i] = *(const f16x8*)(A + r * 128 + ((g ^ (r & 7)) * 16));
      }
#pragma unroll
      for (int j = 0; j < 4; ++j) {
        int r = wc + j * 16 + fr;
        br[j] = *(const f16x8*)(Bb_ + r * 128 + ((g ^ (r & 7)) * 16));
      }
#pragma unroll
      for (int i = 0; i < 4; ++i)
#pragma unroll
        for (int j = 0; j < 4; ++j)
          acc[i][j] = __builtin_amdgcn_mfma_f32_16x16x32_f16(ar[i], br[j], acc[i][j], 0, 0, 0);
    }
    __syncthreads();
  }
  // epilogue: exp (masked -> 1e-6), pack pairs, write swizzled Ph (aliased over A-bufs)
  char* Ph = smem;
  float* rp = (float*)(smem + 64 * 1024);
#pragma unroll
  for (int i = 0; i < 4; ++i)
#pragma unroll
    for (int j = 0; j < 4; ++j) {
      float ev[4];
#pragma unroll
      for (int r = 0; r < 4; ++r) {
        int gl = l0 + wr + i * 16 + hi * 4 + r;
        int gm = m0 + wc + j * 16 + fr;
        ev[r] = (gm <= gl + BAND) ? __expf(acc[i][j][r] * SCALE) : 1e-6f;
      }
#pragma unroll
      for (int r = 0; r < 4; ++r) {
        float p = __shfl_xor(ev[r], 1);
        if (!(fr & 1)) {
          int lrow = wr + i * 16 + hi * 4 + r;
          int mcol = wc + j * 16 + fr;
          f16x2 h2;
          h2[0] = (_Float16)ev[r];
          h2[1] = (_Float16)p;
          *(f16x2*)(Ph + lrow * 256 + ((mcol * 2) ^ ((lrow & 7) << 4))) = h2;
        }
      }
    }
  __syncthreads();
  // cooperative: Ph -> global att_h (coalesced 16B) + per-row sums
#pragma unroll
  for (int s = 0; s < 8; ++s) {
    int idx2 = t + 256 * s;
    int row = idx2 >> 4, ch = idx2 & 15;
    f16x8 v = *(const f16x8*)(Ph + row * 256 + ((ch * 16) ^ ((row & 7) << 4)));
    *(f16x8*)(atth + ((size_t)b * L + l0 + row) * L + m0 + ch * 8) = v;
    float sm = 0.f;
#pragma unroll
    for (int e = 0; e < 8; ++e) sm += (float)v[e];
    sm += __shfl_xor(sm, 1);
    sm += __shfl_xor(sm, 2);
    sm += __shfl_xor(sm, 4);
    sm += __shfl_xor(sm, 8);
    if ((t & 15) == 0) rp[row] = sm;
  }
  __syncthreads();
  if (t < 128) partials[((size_t)b * 16 + mi) * L + l0 + t] = rp[t];
}

// K2: per (b, 32-row l strip): inline rinv, then m-steps of 64.
//     P tile double-buffered in LDS (8KB total); V loaded DIRECTLY into MFMA
//     fragments from global (wave-private rows, L2-resident per XCD).
__global__ __launch_bounds__(512) void k_fused(const _Float16* __restrict__ Vh,
                                               const _Float16* __restrict__ atth,
                                               const float* __restrict__ partials,
                                               float* __restrict__ att,
                                               float* __restrict__ out) {
  const int b = blockIdx.x & 7, li = blockIdx.x >> 3;  // b fastest: batch->XCD
  const int l0 = li * 32;
  const int nsteps = min(32, (l0 + 1120 + 63) >> 6);   // 64-col steps (band cover)
  __shared__ char smem[8 * 1024];    // P0 @0, P1 @4K (32x64 fp16 swizzled)
  __shared__ float rinvS[32];
  const _Float16* Vb = Vh + (size_t)b * C * L;
  const _Float16* ab = atth + (size_t)b * L * L;
  float* attb = att + (size_t)b * L * L;
  float* outb = out + (size_t)b * C * L;
  const int t = threadIdx.x, lane = t & 63, wv = t >> 6;
  const int fr = lane & 15, hi = lane >> 4;
  const int cbase = wv * 32;

  auto stageP = [&](int buf, int s) {
    if (t < 256) {
      int row = t >> 3, seg = t & 7, g = seg ^ (row & 7);
      gload_lds16(ab + (size_t)(l0 + row) * L + s * 64 + g * 8,
                  smem + buf * 4096 + t * 16);
    }
  };

  stageP(0, 0);
  // inline rinv: 16 threads per row, one partial each (or analytic for skipped)
  {
    int row = t >> 4, mi = t & 15;
    int l = l0 + row;
    int nsum = min(16, (l >> 7) + 10);
    float v = (mi < nsum) ? partials[((size_t)b * 16 + mi) * L + l] : 1.28e-4f;
    v += __shfl_xor(v, 1);
    v += __shfl_xor(v, 2);
    v += __shfl_xor(v, 4);
    v += __shfl_xor(v, 8);
    if (mi == 0) rinvS[row] = 1.f / v;
  }
  __syncthreads();
  const float rv_row = rinvS[t >> 4];
  float rvj[2];
#pragma unroll
  for (int j = 0; j < 2; ++j) rvj[j] = rinvS[j * 16 + fr];
  f32x4_t acc[2][2] = {};

  for (int s = 0; s < nsteps; ++s) {
    const int cur = s & 1;
    if (s + 1 < nsteps) stageP(cur ^ 1, s + 1);
    const int m0 = s * 64;
    const char* Pcur = smem + cur * 4096;
    // V fragments direct from global (wave-private rows; L2-resident)
    f16x8 va[2][2];
#pragma unroll
    for (int kk = 0; kk < 2; ++kk)
#pragma unroll
      for (int i = 0; i < 2; ++i)
        va[kk][i] = *(const f16x8*)(Vb + (size_t)(cbase + i * 16 + fr) * L +
                                    m0 + (kk * 4 + hi) * 8);
    // normalized fp32 att write from P tile (16 threads/row, 16B each)
    {
      int row = t >> 4, ch = (t & 15) >> 1, half = t & 1;
      f16x4 h = *(const f16x4*)(Pcur + row * 128 + ((ch ^ (row & 7)) * 16) + half * 8);
      float4 o = make_float4((float)h[0] * rv_row, (float)h[1] * rv_row,
                             (float)h[2] * rv_row, (float)h[3] * rv_row);
      *(float4*)(attb + (size_t)(l0 + row) * L + m0 + ch * 8 + half * 4) = o;
    }
    // PV MFMA: out[c,l] += V[c,m]*P[l,m]
#pragma unroll
    for (int kk = 0; kk < 2; ++kk) {
      f16x8 b_[2];
      const int g = kk * 4 + hi;
#pragma unroll
      for (int j = 0; j < 2; ++j) {
        int r = j * 16 + fr;
        b_[j] = *(const f16x8*)(Pcur + r * 128 + ((g ^ (r & 7)) * 16));
      }
#pragma unroll
      for (int i = 0; i < 2; ++i)
#pragma unroll
        for (int j = 0; j < 2; ++j)
          acc[i][j] = __builtin_amdgcn_mfma_f32_16x16x32_f16(va[kk][i], b_[j], acc[i][j], 0, 0, 0);
    }
    __syncthreads();
  }
  // masked tail fill: cols [Mcov, 2048) = 1e-6 * rinv
  const int Mcov = nsteps * 64;
  if (Mcov < L) {
    const int row = t >> 4;
    const int npt = (L - Mcov) >> 6;  // float4s per thread (16 threads/row)
    const float cv = 1e-6f * rv_row;
    const float4 cst = make_float4(cv, cv, cv, cv);
    float* dst = attb + (size_t)(l0 + row) * L;
    for (int u = 0; u < npt; ++u) {
      int m = Mcov + ((t & 15) + u * 16) * 4;
      *(float4*)(dst + m) = cst;
    }
  }
  // out epilogue with rinv scale
#pragma unroll
  for (int i = 0; i < 2; ++i)
#pragma unroll
    for (int j = 0; j < 2; ++j)
#pragma unroll
      for (int r = 0; r < 4; ++r) {
        int c = cbase + i * 16 + hi * 4 + r;
        int l = j * 16 + fr;
        outb[(size_t)c * L + l0 + l] = acc[i][j][r] * rvj[j];
      }
}

extern "C" void kernel_launch(void* const* d_in, const int* in_sizes, int n_in,
                              void* d_out, int out_size, void* d_ws, size_t ws_size,
                              hipStream_t stream) {
  const float* Q = (const float*)d_in[0];
  const float* K = (const float*)d_in[1];
  const float* V = (const float*)d_in[2];
  float* out = (float*)d_out;
  float* att = out + (size_t)B * C * L;

  char* w = (char*)d_ws;
  const size_t szT = (size_t)B * L * C * 2;           // 8 MiB per fp16 tensor
  _Float16* Qh = (_Float16*)(w);
  _Float16* Kh = (_Float16*)(w + szT);
  _Float16* Vh = (_Float16*)(w + 2 * szT);
  _Float16* atth = (_Float16*)(w + 3 * szT);          // (B,L,L) fp16 = 64 MiB
  float* partials = (float*)(w + 3 * szT + (size_t)B * L * L * 2);

  k_prep<<<dim3(32, 4, 16), 256, 0, stream>>>(Q, K, Qh, Kh);
  k_energy_exp<<<2048, 256, 0, stream>>>(Qh, Kh, V, Vh, atth, partials);
  k_fused<<<512, 512, 0, stream>>>(Vh, atth, partials, att, out);
}

// Round 9
// 117.962 us; speedup vs baseline: 1.2303x; 1.2303x over previous
//
#include <hip/hip_runtime.h>
#include <hip/hip_bf16.h>
#include <stdint.h>

// AttentionHelper: B=8, C=256, L=2048
//   energy[b,l,m] = sum_c Q[b,c,l]*K[b,c,m]
//   A = softmax_m(energy/16 banded; masked -> unnormalized exp = 1e-6)
//   out[b,c,l] = sum_m V[b,c,m]*A[b,l,m]
// R6 structure (known-good 107us): k_prep (transpose/cvt) -> k_energy_exp
// (QK^T -> exp fp16 + rowsum partials, b-fastest XCD pin) -> k_fused.
// R9 change: k_fused split along c -> 1024 blocks x 256thr, 40KB LDS,
// 4 blocks/CU, half the bytes/threads per barrier.
// Lessons kept: no NT stores (R7: vmcnt drain waits HBM acks, +30us);
// V must be LDS-staged (R8: direct global V reads uncoalesced, +38us).

namespace {
constexpr int B = 8, C = 256, L = 2048;
constexpr int BAND = L / 2 + 64;   // 1088
constexpr float SCALE = 0.0625f;   // 1/sqrt(256)
}

typedef _Float16 f16x8 __attribute__((ext_vector_type(8)));
typedef _Float16 f16x4 __attribute__((ext_vector_type(4)));
typedef _Float16 f16x2 __attribute__((ext_vector_type(2)));
typedef float f32x4_t __attribute__((ext_vector_type(4)));

__device__ __forceinline__ void gload_lds16(const void* g, void* l) {
  __builtin_amdgcn_global_load_lds((const __attribute__((address_space(1))) void*)g,
                                   (__attribute__((address_space(3))) void*)l,
                                   16, 0, 0);
}

// K0: z<16: transpose (C,L)fp32 -> (L,C)fp16 for Q (z<8) / K (z>=8), 32l x 64c tiles.
//     z>=16: V fp32 -> fp16 elementwise (2 float4 per thread).
__global__ __launch_bounds__(256) void k_prep(const float* __restrict__ Q,
                                              const float* __restrict__ K,
                                              const float* __restrict__ V,
                                              _Float16* __restrict__ Qh,
                                              _Float16* __restrict__ Kh,
                                              _Float16* __restrict__ Vh) {
  const int z = blockIdx.z;
  if (z < 16) {
    __shared__ float tile[64][33];
    const float* src = (z < 8) ? Q : K;
    _Float16* dst = (z < 8) ? Qh : Kh;
    const int b = z & 7;
    const int l0 = blockIdx.x * 32, c0 = blockIdx.y * 64;
    const float* s = src + (size_t)b * C * L;
    const int tx = threadIdx.x, ty = threadIdx.y;
#pragma unroll
    for (int i = 0; i < 8; ++i)
      tile[ty + 8 * i][tx] = s[(size_t)(c0 + ty + 8 * i) * L + l0 + tx];
    __syncthreads();
    _Float16* d = dst + (size_t)b * L * C;
#pragma unroll
    for (int i = 0; i < 4; ++i) {
      int l = ty + 8 * i;
      f16x2 h2;
      h2[0] = (_Float16)tile[2 * tx][l];
      h2[1] = (_Float16)tile[2 * tx + 1][l];
      *(f16x2*)(d + (size_t)(l0 + l) * C + c0 + 2 * tx) = h2;
    }
  } else {
    int blk = ((z - 16) * 4 + blockIdx.y) * 64 + blockIdx.x;  // 0..2047
    int tid = blk * 256 + threadIdx.y * 32 + threadIdx.x;     // 0..524287
#pragma unroll
    for (int u = 0; u < 2; ++u) {
      int i = tid + u * 524288;
      float4 v = ((const float4*)V)[i];
      f16x4 o = { (_Float16)v.x, (_Float16)v.y, (_Float16)v.z, (_Float16)v.w };
      ((f16x4*)Vh)[i] = o;
    }
  }
}

// K1: QK^T GEMM (128x128 tile, BK=64, double-buffered prefetch) -> exp ->
//     fp16 att_h + rowsum partials. 1D grid, b fastest (batch -> XCD L2 pin).
__global__ __launch_bounds__(256) void k_energy_exp(const _Float16* __restrict__ Qh,
                                                    const _Float16* __restrict__ Kh,
                                                    _Float16* __restrict__ atth,
                                                    float* __restrict__ partials) {
  const int idx = blockIdx.x;
  const int b = idx & 7, li = (idx >> 3) & 15, mi = idx >> 7;
  if (mi >= li + 10) return;  // fully-masked tile: never read downstream
  const int m0 = mi * 128, l0 = li * 128;
  __shared__ char smem[66 * 1024];
  const _Float16* Qb = Qh + (size_t)b * L * C;
  const _Float16* Kb = Kh + (size_t)b * L * C;
  const int t = threadIdx.x, lane = t & 63, wv = t >> 6;
  const int wr = (wv >> 1) * 64, wc = (wv & 1) * 64;
  const int fr = lane & 15, hi = lane >> 4;
  f32x4_t acc[4][4] = {};

  auto stage = [&](int buf, int k0) {
#pragma unroll
    for (int ss = 0; ss < 4; ++ss) {
      int q = ss * 256 + t;                 // 1024 chunks of 16B per matrix
      int row = q >> 3, seg = q & 7, g = seg ^ (row & 7);
      gload_lds16(Qb + (size_t)(l0 + row) * C + k0 + g * 8,
                  smem + buf * 16384 + q * 16);
      gload_lds16(Kb + (size_t)(m0 + row) * C + k0 + g * 8,
                  smem + 32768 + buf * 16384 + q * 16);
    }
  };

  stage(0, 0);
  __syncthreads();
#pragma unroll
  for (int s = 0; s < 4; ++s) {
    if (s < 3) stage((s + 1) & 1, (s + 1) * 64);
    const char* A = smem + (s & 1) * 16384;
    const char* Bb_ = smem + 32768 + (s & 1) * 16384;
#pragma unroll
    for (int kk = 0; kk < 2; ++kk) {
      f16x8 ar[4], br[4];
      const int g = kk * 4 + hi;
#pragma unroll
      for (int i = 0; i < 4; ++i) {
        int r = wr + i * 16 + fr;
        ar[i] = *(const f16x8*)(A + r * 128 + ((g ^ (r & 7)) * 16));
      }
#pragma unroll
      for (int j = 0; j < 4; ++j) {
        int r = wc + j * 16 + fr;
        br[j] = *(const f16x8*)(Bb_ + r * 128 + ((g ^ (r & 7)) * 16));
      }
#pragma unroll
      for (int i = 0; i < 4; ++i)
#pragma unroll
        for (int j = 0; j < 4; ++j)
          acc[i][j] = __builtin_amdgcn_mfma_f32_16x16x32_f16(ar[i], br[j], acc[i][j], 0, 0, 0);
    }
    __syncthreads();
  }
  // epilogue: exp (masked -> 1e-6), pack pairs, write swizzled Ph (aliased over A-bufs)
  char* Ph = smem;
  float* rp = (float*)(smem + 64 * 1024);
#pragma unroll
  for (int i = 0; i < 4; ++i)
#pragma unroll
    for (int j = 0; j < 4; ++j) {
      float ev[4];
#pragma unroll
      for (int r = 0; r < 4; ++r) {
        int gl = l0 + wr + i * 16 + hi * 4 + r;
        int gm = m0 + wc + j * 16 + fr;
        ev[r] = (gm <= gl + BAND) ? __expf(acc[i][j][r] * SCALE) : 1e-6f;
      }
#pragma unroll
      for (int r = 0; r < 4; ++r) {
        float p = __shfl_xor(ev[r], 1);
        if (!(fr & 1)) {
          int lrow = wr + i * 16 + hi * 4 + r;
          int mcol = wc + j * 16 + fr;
          f16x2 h2;
          h2[0] = (_Float16)ev[r];
          h2[1] = (_Float16)p;
          *(f16x2*)(Ph + lrow * 256 + ((mcol * 2) ^ ((lrow & 7) << 4))) = h2;
        }
      }
    }
  __syncthreads();
  // cooperative: Ph -> global att_h (coalesced 16B) + per-row sums
#pragma unroll
  for (int s = 0; s < 8; ++s) {
    int idx2 = t + 256 * s;
    int row = idx2 >> 4, ch = idx2 & 15;
    f16x8 v = *(const f16x8*)(Ph + row * 256 + ((ch * 16) ^ ((row & 7) << 4)));
    *(f16x8*)(atth + ((size_t)b * L + l0 + row) * L + m0 + ch * 8) = v;
    float sm = 0.f;
#pragma unroll
    for (int e = 0; e < 8; ++e) sm += (float)v[e];
    sm += __shfl_xor(sm, 1);
    sm += __shfl_xor(sm, 2);
    sm += __shfl_xor(sm, 4);
    sm += __shfl_xor(sm, 8);
    if ((t & 15) == 0) rp[row] = sm;
  }
  __syncthreads();
  if (t < 128) partials[((size_t)b * 16 + mi) * L + l0 + t] = rp[t];
}

// K2: per (b, ct in {0,1}, 32-row l strip): 256 thr, 40KB LDS (4 blocks/CU).
//     Block owns c-half [ct*128, ct*128+128) x 32 l-rows. Inline rinv, then
//     m-steps of 64, double-buffered: fp32 att write (rows ct*16..+16) AND
//     out[c,l] += V[c,m]*P[l,m].
__global__ __launch_bounds__(256) void k_fused(const _Float16* __restrict__ Vh,
                                               const _Float16* __restrict__ atth,
                                               const float* __restrict__ partials,
                                               float* __restrict__ att,
                                               float* __restrict__ out) {
  const int idx = blockIdx.x;
  const int b = idx & 7, ct = (idx >> 3) & 1, li = idx >> 4;  // b fastest: XCD pin
  const int l0 = li * 32;
  const int nsteps = min(32, (l0 + 1120 + 63) >> 6);   // 64-col steps (band cover)
  __shared__ char smem[40 * 1024];
  // layout: V0 @0, V1 @16K (128x64 fp16); P0 @32K, P1 @36K (32x64 fp16)
  __shared__ float rinvS[32];
  const _Float16* Vb = Vh + (size_t)b * C * L + (size_t)ct * 128 * L;
  const _Float16* ab = atth + (size_t)b * L * L;
  float* attb = att + (size_t)b * L * L;
  float* outb = out + (size_t)b * C * L;
  const int t = threadIdx.x, lane = t & 63, wv = t >> 6;   // wv 0..3
  const int fr = lane & 15, hi = lane >> 4;
  const int cbase = wv * 32;                               // within 128 c-half

  auto stage = [&](int buf, int s) {
    const int m0 = s * 64;
#pragma unroll
    for (int ss = 0; ss < 4; ++ss) {
      int q = ss * 256 + t;                  // V: 1024 chunks (128 rows x 128B)
      int row = q >> 3, seg = q & 7, g = seg ^ (row & 7);
      gload_lds16(Vb + (size_t)row * L + m0 + g * 8, smem + buf * 16384 + q * 16);
    }
    {
      int q = t;                             // P: 256 chunks (32 rows x 128B)
      int row = q >> 3, seg = q & 7, g = seg ^ (row & 7);
      gload_lds16(ab + (size_t)(l0 + row) * L + m0 + g * 8,
                  smem + 32768 + buf * 4096 + q * 16);
    }
  };

  stage(0, 0);
  // inline rinv: 8 threads per row, two partials each (or analytic for skipped)
  {
    int row = t >> 3, mi = t & 7;
    int l = l0 + row;
    int nsum = min(16, (l >> 7) + 10);
    float v = (mi < nsum ? partials[((size_t)b * 16 + mi) * L + l] : 1.28e-4f) +
              (mi + 8 < nsum ? partials[((size_t)b * 16 + mi + 8) * L + l] : 1.28e-4f);
    v += __shfl_xor(v, 1);
    v += __shfl_xor(v, 2);
    v += __shfl_xor(v, 4);
    if (mi == 0) rinvS[row] = 1.f / v;
  }
  __syncthreads();
  const int row_t = ct * 16 + (t >> 4);      // this block's att-write rows
  const float rv_row = rinvS[row_t];
  float rvj[2];
#pragma unroll
  for (int j = 0; j < 2; ++j) rvj[j] = rinvS[j * 16 + fr];
  f32x4_t acc[2][2] = {};

  for (int s = 0; s < nsteps; ++s) {
    const int cur = s & 1;
    if (s + 1 < nsteps) stage(cur ^ 1, s + 1);
    const int m0 = s * 64;
    const char* Vcur = smem + cur * 16384;
    const char* Pcur = smem + 32768 + cur * 4096;
    // normalized fp32 att write from P tile (16 rows, 16 threads/row, 16B each)
    {
      int ch = (t & 15) >> 1, half = t & 1;
      f16x4 h = *(const f16x4*)(Pcur + row_t * 128 + ((ch ^ (row_t & 7)) * 16) + half * 8);
      float4 o = make_float4((float)h[0] * rv_row, (float)h[1] * rv_row,
                             (float)h[2] * rv_row, (float)h[3] * rv_row);
      *(float4*)(attb + (size_t)(l0 + row_t) * L + m0 + ch * 8 + half * 4) = o;
    }
    // PV MFMA: out[c,l] += V[c,m]*P[l,m]
#pragma unroll
    for (int kk = 0; kk < 2; ++kk) {
      f16x8 a_[2], b_[2];
      const int g = kk * 4 + hi;
#pragma unroll
      for (int i = 0; i < 2; ++i) {
        int r = cbase + i * 16 + fr;
        a_[i] = *(const f16x8*)(Vcur + r * 128 + ((g ^ (r & 7)) * 16));
      }
#pragma unroll
      for (int j = 0; j < 2; ++j) {
        int r = j * 16 + fr;
        b_[j] = *(const f16x8*)(Pcur + r * 128 + ((g ^ (r & 7)) * 16));
      }
#pragma unroll
      for (int i = 0; i < 2; ++i)
#pragma unroll
        for (int j = 0; j < 2; ++j)
          acc[i][j] = __builtin_amdgcn_mfma_f32_16x16x32_f16(a_[i], b_[j], acc[i][j], 0, 0, 0);
    }
    __syncthreads();
  }
  // masked tail fill: cols [Mcov, 2048) = 1e-6 * rinv (this block's 16 rows)
  const int Mcov = nsteps * 64;
  if (Mcov < L) {
    const int npt = (L - Mcov) >> 6;  // float4s per thread (16 threads/row)
    const float cv = 1e-6f * rv_row;
    const float4 cst = make_float4(cv, cv, cv, cv);
    float* dst = attb + (size_t)(l0 + row_t) * L;
    for (int u = 0; u < npt; ++u) {
      int m = Mcov + ((t & 15) + u * 16) * 4;
      *(float4*)(dst + m) = cst;
    }
  }
  // out epilogue with rinv scale
#pragma unroll
  for (int i = 0; i < 2; ++i)
#pragma unroll
    for (int j = 0; j < 2; ++j)
#pragma unroll
      for (int r = 0; r < 4; ++r) {
        int c = ct * 128 + cbase + i * 16 + hi * 4 + r;
        int l = j * 16 + fr;
        outb[(size_t)c * L + l0 + l] = acc[i][j][r] * rvj[j];
      }
}

extern "C" void kernel_launch(void* const* d_in, const int* in_sizes, int n_in,
                              void* d_out, int out_size, void* d_ws, size_t ws_size,
                              hipStream_t stream) {
  const float* Q = (const float*)d_in[0];
  const float* K = (const float*)d_in[1];
  const float* V = (const float*)d_in[2];
  float* out = (float*)d_out;
  float* att = out + (size_t)B * C * L;

  char* w = (char*)d_ws;
  const size_t szT = (size_t)B * L * C * 2;           // 8 MiB per fp16 tensor
  _Float16* Qh = (_Float16*)(w);
  _Float16* Kh = (_Float16*)(w + szT);
  _Float16* Vh = (_Float16*)(w + 2 * szT);
  _Float16* atth = (_Float16*)(w + 3 * szT);          // (B,L,L) fp16 = 64 MiB
  float* partials = (float*)(w + 3 * szT + (size_t)B * L * L * 2);

  k_prep<<<dim3(64, 4, 24), dim3(32, 8), 0, stream>>>(Q, K, V, Qh, Kh, Vh);
  k_energy_exp<<<2048, 256, 0, stream>>>(Qh, Kh, atth, partials);
  k_fused<<<1024, 256, 0, stream>>>(Vh, atth, partials, att, out);
}

// Round 11
// 107.716 us; speedup vs baseline: 1.3473x; 1.0951x over previous
//
#include <hip/hip_runtime.h>
#include <hip/hip_bf16.h>
#include <stdint.h>

// AttentionHelper: B=8, C=256, L=2048
//   energy[b,l,m] = sum_c Q[b,c,l]*K[b,c,m]
//   A = softmax_m(energy/16 banded; masked -> unnormalized exp = 1e-6)
//   out[b,c,l] = sum_m V[b,c,m]*A[b,l,m]
// R6 structure + R11 counted-vmcnt double-barrier K-loops:
//   stage(s+1) -> vmcnt(covers stage(s) only) -> s_barrier -> compute(s)
//   -> s_barrier (WAR: reads of buf done before next overwrite).
// R10 lesson: single-barrier counted loop races (stage(s+1) vs compute(s-1)
// ds_reads); mixed-wave vmcnt constants must be per-wave.
// Other lessons: no NT stores (R7); V LDS-staged (R8); R6 tile shapes (R9).

namespace {
constexpr int B = 8, C = 256, L = 2048;
constexpr int BAND = L / 2 + 64;   // 1088
constexpr float SCALE = 0.0625f;   // 1/sqrt(256)
}

typedef _Float16 f16x8 __attribute__((ext_vector_type(8)));
typedef _Float16 f16x4 __attribute__((ext_vector_type(4)));
typedef _Float16 f16x2 __attribute__((ext_vector_type(2)));
typedef float f32x4_t __attribute__((ext_vector_type(4)));

__device__ __forceinline__ void gload_lds16(const void* g, void* l) {
  __builtin_amdgcn_global_load_lds((const __attribute__((address_space(1))) void*)g,
                                   (__attribute__((address_space(3))) void*)l,
                                   16, 0, 0);
}

// K0: z<16: transpose (C,L)fp32 -> (L,C)fp16 for Q (z<8) / K (z>=8), 32l x 64c tiles.
//     z>=16: V fp32 -> fp16 elementwise (2 float4 per thread).
__global__ __launch_bounds__(256) void k_prep(const float* __restrict__ Q,
                                              const float* __restrict__ K,
                                              const float* __restrict__ V,
                                              _Float16* __restrict__ Qh,
                                              _Float16* __restrict__ Kh,
                                              _Float16* __restrict__ Vh) {
  const int z = blockIdx.z;
  if (z < 16) {
    __shared__ float tile[64][33];
    const float* src = (z < 8) ? Q : K;
    _Float16* dst = (z < 8) ? Qh : Kh;
    const int b = z & 7;
    const int l0 = blockIdx.x * 32, c0 = blockIdx.y * 64;
    const float* s = src + (size_t)b * C * L;
    const int tx = threadIdx.x, ty = threadIdx.y;
#pragma unroll
    for (int i = 0; i < 8; ++i)
      tile[ty + 8 * i][tx] = s[(size_t)(c0 + ty + 8 * i) * L + l0 + tx];
    __syncthreads();
    _Float16* d = dst + (size_t)b * L * C;
#pragma unroll
    for (int i = 0; i < 4; ++i) {
      int l = ty + 8 * i;
      f16x2 h2;
      h2[0] = (_Float16)tile[2 * tx][l];
      h2[1] = (_Float16)tile[2 * tx + 1][l];
      *(f16x2*)(d + (size_t)(l0 + l) * C + c0 + 2 * tx) = h2;
    }
  } else {
    int blk = ((z - 16) * 4 + blockIdx.y) * 64 + blockIdx.x;  // 0..2047
    int tid = blk * 256 + threadIdx.y * 32 + threadIdx.x;     // 0..524287
#pragma unroll
    for (int u = 0; u < 2; ++u) {
      int i = tid + u * 524288;
      float4 v = ((const float4*)V)[i];
      f16x4 o = { (_Float16)v.x, (_Float16)v.y, (_Float16)v.z, (_Float16)v.w };
      ((f16x4*)Vh)[i] = o;
    }
  }
}

// K1: QK^T GEMM (128x128 tile, BK=64, dbuf, counted-vmcnt 2-barrier loop)
//     -> exp -> fp16 att_h + rowsum partials. 1D grid, b fastest (XCD pin).
__global__ __launch_bounds__(256) void k_energy_exp(const _Float16* __restrict__ Qh,
                                                    const _Float16* __restrict__ Kh,
                                                    _Float16* __restrict__ atth,
                                                    float* __restrict__ partials) {
  const int idx = blockIdx.x;
  const int b = idx & 7, li = (idx >> 3) & 15, mi = idx >> 7;
  if (mi >= li + 10) return;  // fully-masked tile: never read downstream
  const int m0 = mi * 128, l0 = li * 128;
  __shared__ char smem[66 * 1024];
  const _Float16* Qb = Qh + (size_t)b * L * C;
  const _Float16* Kb = Kh + (size_t)b * L * C;
  const int t = threadIdx.x, lane = t & 63, wv = t >> 6;
  const int wr = (wv >> 1) * 64, wc = (wv & 1) * 64;
  const int fr = lane & 15, hi = lane >> 4;
  f32x4_t acc[4][4] = {};

  auto stage = [&](int buf, int k0) {
#pragma unroll
    for (int ss = 0; ss < 4; ++ss) {
      int q = ss * 256 + t;                 // 1024 chunks of 16B per matrix
      int row = q >> 3, seg = q & 7, g = seg ^ (row & 7);
      gload_lds16(Qb + (size_t)(l0 + row) * C + k0 + g * 8,
                  smem + buf * 16384 + q * 16);
      gload_lds16(Kb + (size_t)(m0 + row) * C + k0 + g * 8,
                  smem + 32768 + buf * 16384 + q * 16);
    }
  };

  stage(0, 0);  // 8 vm ops in flight per thread
#pragma unroll
  for (int s = 0; s < 4; ++s) {
    if (s < 3) {
      stage((s + 1) & 1, (s + 1) * 64);
      // queue: [stage(s):8][stage(s+1):8] -> <=8 left means stage(s) done
      asm volatile("s_waitcnt vmcnt(8)" ::: "memory");
    } else {
      asm volatile("s_waitcnt vmcnt(0)" ::: "memory");
    }
    __builtin_amdgcn_s_barrier();          // data-ready for buf s&1
    const char* A = smem + (s & 1) * 16384;
    const char* Bb_ = smem + 32768 + (s & 1) * 16384;
#pragma unroll
    for (int kk = 0; kk < 2; ++kk) {
      f16x8 ar[4], br[4];
      const int g = kk * 4 + hi;
#pragma unroll
      for (int i = 0; i < 4; ++i) {
        int r = wr + i * 16 + fr;
        ar[i] = *(const f16x8*)(A + r * 128 + ((g ^ (r & 7)) * 16));
      }
#pragma unroll
      for (int j = 0; j < 4; ++j) {
        int r = wc + j * 16 + fr;
        br[j] = *(const f16x8*)(Bb_ + r * 128 + ((g ^ (r & 7)) * 16));
      }
#pragma unroll
      for (int i = 0; i < 4; ++i)
#pragma unroll
        for (int j = 0; j < 4; ++j)
          acc[i][j] = __builtin_amdgcn_mfma_f32_16x16x32_f16(ar[i], br[j], acc[i][j], 0, 0, 0);
    }
    __builtin_amdgcn_s_barrier();          // WAR: buf s&1 reads done before overwrite
  }
  // epilogue: exp (masked -> 1e-6), pack pairs, write swizzled Ph (aliased over A-bufs)
  char* Ph = smem;
  float* rp = (float*)(smem + 64 * 1024);
#pragma unroll
  for (int i = 0; i < 4; ++i)
#pragma unroll
    for (int j = 0; j < 4; ++j) {
      float ev[4];
#pragma unroll
      for (int r = 0; r < 4; ++r) {
        int gl = l0 + wr + i * 16 + hi * 4 + r;
        int gm = m0 + wc + j * 16 + fr;
        ev[r] = (gm <= gl + BAND) ? __expf(acc[i][j][r] * SCALE) : 1e-6f;
      }
#pragma unroll
      for (int r = 0; r < 4; ++r) {
        float p = __shfl_xor(ev[r], 1);
        if (!(fr & 1)) {
          int lrow = wr + i * 16 + hi * 4 + r;
          int mcol = wc + j * 16 + fr;
          f16x2 h2;
          h2[0] = (_Float16)ev[r];
          h2[1] = (_Float16)p;
          *(f16x2*)(Ph + lrow * 256 + ((mcol * 2) ^ ((lrow & 7) << 4))) = h2;
        }
      }
    }
  __syncthreads();
  // cooperative: Ph -> global att_h (coalesced 16B) + per-row sums
#pragma unroll
  for (int s = 0; s < 8; ++s) {
    int idx2 = t + 256 * s;
    int row = idx2 >> 4, ch = idx2 & 15;
    f16x8 v = *(const f16x8*)(Ph + row * 256 + ((ch * 16) ^ ((row & 7) << 4)));
    *(f16x8*)(atth + ((size_t)b * L + l0 + row) * L + m0 + ch * 8) = v;
    float sm = 0.f;
#pragma unroll
    for (int e = 0; e < 8; ++e) sm += (float)v[e];
    sm += __shfl_xor(sm, 1);
    sm += __shfl_xor(sm, 2);
    sm += __shfl_xor(sm, 4);
    sm += __shfl_xor(sm, 8);
    if ((t & 15) == 0) rp[row] = sm;
  }
  __syncthreads();
  if (t < 128) partials[((size_t)b * 16 + mi) * L + l0 + t] = rp[t];
}

// K2: per (b, 32-row l strip): inline rinv, then m-steps of 64, double-buffered
//     counted-vmcnt 2-barrier loop: fp32 att write (rv*P) AND PV MFMA.
__global__ __launch_bounds__(512) void k_fused(const _Float16* __restrict__ Vh,
                                               const _Float16* __restrict__ atth,
                                               const float* __restrict__ partials,
                                               float* __restrict__ att,
                                               float* __restrict__ out) {
  const int b = blockIdx.x & 7, li = blockIdx.x >> 3;  // b fastest: batch->XCD
  const int l0 = li * 32;
  const int nsteps = min(32, (l0 + 1120 + 63) >> 6);   // 64-col steps (band cover)
  __shared__ char smem[72 * 1024];
  // layout: V0 @0, V1 @32K (256x64 fp16); P0 @64K, P1 @68K (32x64 fp16)
  __shared__ float rinvS[32];
  const _Float16* Vb = Vh + (size_t)b * C * L;
  const _Float16* ab = atth + (size_t)b * L * L;
  float* attb = att + (size_t)b * L * L;
  float* outb = out + (size_t)b * C * L;
  const int t = threadIdx.x, lane = t & 63, wv = t >> 6;
  const int fr = lane & 15, hi = lane >> 4;
  const int cbase = wv * 32;

  auto stage = [&](int buf, int s) {
    const int m0 = s * 64;
#pragma unroll
    for (int ss = 0; ss < 4; ++ss) {
      int q = ss * 512 + t;                  // V: 2048 chunks (256 rows x 128B)
      int row = q >> 3, seg = q & 7, g = seg ^ (row & 7);
      gload_lds16(Vb + (size_t)row * L + m0 + g * 8, smem + buf * 32768 + q * 16);
    }
    if (t < 256) {
      int q = t;                             // P: 256 chunks (32 rows x 128B)
      int row = q >> 3, seg = q & 7, g = seg ^ (row & 7);
      gload_lds16(ab + (size_t)(l0 + row) * L + m0 + g * 8,
                  smem + 65536 + buf * 4096 + q * 16);
    }
  };

  stage(0, 0);
  // inline rinv; the partials read (issued last) forces vmcnt->0, so stage(0)
  // is also complete before the __syncthreads below.
  {
    int row = t >> 4, mi = t & 15;
    int l = l0 + row;
    int nsum = min(16, (l >> 7) + 10);
    float v = (mi < nsum) ? partials[((size_t)b * 16 + mi) * L + l] : 1.28e-4f;
    v += __shfl_xor(v, 1);
    v += __shfl_xor(v, 2);
    v += __shfl_xor(v, 4);
    v += __shfl_xor(v, 8);
    if (mi == 0) rinvS[row] = 1.f / v;
  }
  __syncthreads();
  const float rv_row = rinvS[t >> 4];
  float rvj[2];
#pragma unroll
  for (int j = 0; j < 2; ++j) rvj[j] = rinvS[j * 16 + fr];
  f32x4_t acc[2][2] = {};

  for (int s = 0; s < nsteps; ++s) {
    const int cur = s & 1;
    if (s + 1 < nsteps) {
      stage(cur ^ 1, s + 1);
      // queue: [stage(s):5|4][store(s-1):1][stage(s+1):5|4]
      // waves 0-3 (5-op stage): drain to 6 -> stage(s) complete
      // waves 4-7 (4-op stage): drain to 5
      if (t < 256) asm volatile("s_waitcnt vmcnt(6)" ::: "memory");
      else         asm volatile("s_waitcnt vmcnt(5)" ::: "memory");
    } else {
      // queue: [stage(s):5|4][store(s-1):1] -> drain to 1
      asm volatile("s_waitcnt vmcnt(1)" ::: "memory");
    }
    __builtin_amdgcn_s_barrier();            // data-ready for buffers 'cur'
    const int m0 = s * 64;
    const char* Vcur = smem + cur * 32768;
    const char* Pcur = smem + 65536 + cur * 4096;
    // normalized fp32 att write from P tile (16 threads/row, 16B each)
    {
      int row = t >> 4, ch = (t & 15) >> 1, half = t & 1;
      f16x4 h = *(const f16x4*)(Pcur + row * 128 + ((ch ^ (row & 7)) * 16) + half * 8);
      float4 o = make_float4((float)h[0] * rv_row, (float)h[1] * rv_row,
                             (float)h[2] * rv_row, (float)h[3] * rv_row);
      *(float4*)(attb + (size_t)(l0 + row) * L + m0 + ch * 8 + half * 4) = o;
    }
    // PV MFMA: out[c,l] += V[c,m]*P[l,m]
#pragma unroll
    for (int kk = 0; kk < 2; ++kk) {
      f16x8 a_[2], b_[2];
      const int g = kk * 4 + hi;
#pragma unroll
      for (int i = 0; i < 2; ++i) {
        int r = cbase + i * 16 + fr;
        a_[i] = *(const f16x8*)(Vcur + r * 128 + ((g ^ (r & 7)) * 16));
      }
#pragma unroll
      for (int j = 0; j < 2; ++j) {
        int r = j * 16 + fr;
        b_[j] = *(const f16x8*)(Pcur + r * 128 + ((g ^ (r & 7)) * 16));
      }
#pragma unroll
      for (int i = 0; i < 2; ++i)
#pragma unroll
        for (int j = 0; j < 2; ++j)
          acc[i][j] = __builtin_amdgcn_mfma_f32_16x16x32_f16(a_[i], b_[j], acc[i][j], 0, 0, 0);
    }
    __builtin_amdgcn_s_barrier();            // WAR: 'cur' reads done before overwrite
  }
  // masked tail fill: cols [Mcov, 2048) = 1e-6 * rinv
  const int Mcov = nsteps * 64;
  if (Mcov < L) {
    const int row = t >> 4;
    const int npt = (L - Mcov) >> 6;  // float4s per thread (16 threads/row)
    const float cv = 1e-6f * rv_row;
    const float4 cst = make_float4(cv, cv, cv, cv);
    float* dst = attb + (size_t)(l0 + row) * L;
    for (int u = 0; u < npt; ++u) {
      int m = Mcov + ((t & 15) + u * 16) * 4;
      *(float4*)(dst + m) = cst;
    }
  }
  // out epilogue with rinv scale
#pragma unroll
  for (int i = 0; i < 2; ++i)
#pragma unroll
    for (int j = 0; j < 2; ++j)
#pragma unroll
      for (int r = 0; r < 4; ++r) {
        int c = cbase + i * 16 + hi * 4 + r;
        int l = j * 16 + fr;
        outb[(size_t)c * L + l0 + l] = acc[i][j][r] * rvj[j];
      }
}

extern "C" void kernel_launch(void* const* d_in, const int* in_sizes, int n_in,
                              void* d_out, int out_size, void* d_ws, size_t ws_size,
                              hipStream_t stream) {
  const float* Q = (const float*)d_in[0];
  const float* K = (const float*)d_in[1];
  const float* V = (const float*)d_in[2];
  float* out = (float*)d_out;
  float* att = out + (size_t)B * C * L;

  char* w = (char*)d_ws;
  const size_t szT = (size_t)B * L * C * 2;           // 8 MiB per fp16 tensor
  _Float16* Qh = (_Float16*)(w);
  _Float16* Kh = (_Float16*)(w + szT);
  _Float16* Vh = (_Float16*)(w + 2 * szT);
  _Float16* atth = (_Float16*)(w + 3 * szT);          // (B,L,L) fp16 = 64 MiB
  float* partials = (float*)(w + 3 * szT + (size_t)B * L * L * 2);

  k_prep<<<dim3(64, 4, 24), dim3(32, 8), 0, stream>>>(Q, K, V, Qh, Kh, Vh);
  k_energy_exp<<<2048, 256, 0, stream>>>(Qh, Kh, atth, partials);
  k_fused<<<512, 512, 0, stream>>>(Vh, atth, partials, att, out);
}

// Round 12
// 96.709 us; speedup vs baseline: 1.5006x; 1.1138x over previous
//
#include <hip/hip_runtime.h>
#include <hip/hip_bf16.h>
#include <stdint.h>

// AttentionHelper: B=8, C=256, L=2048
//   energy[b,l,m] = sum_c Q[b,c,l]*K[b,c,m]
//   A = softmax_m(energy/16 banded; masked -> unnormalized exp = 1e-6)
//   out[b,c,l] = sum_m V[b,c,m]*A[b,l,m]
// R12: occupancy-first. Single-buffered LDS staging in both GEMMs:
//   k_energy 33KB -> 4 blocks/CU (was 66KB/2); k_fused 36.5KB -> 4 blocks/CU
//   (was 72KB/2). Intra-block double-buffering removed: R10/R11 proved the
//   barrier drain is covered by inter-block TLP (m114), not in-block ILP.
// Lessons: no NT stores (R7); V LDS-staged (R8); R6 tile shapes (R9);
// counted-vmcnt gave 0 (R11).

namespace {
constexpr int B = 8, C = 256, L = 2048;
constexpr int BAND = L / 2 + 64;   // 1088
constexpr float SCALE = 0.0625f;   // 1/sqrt(256)
}

typedef _Float16 f16x8 __attribute__((ext_vector_type(8)));
typedef _Float16 f16x4 __attribute__((ext_vector_type(4)));
typedef _Float16 f16x2 __attribute__((ext_vector_type(2)));
typedef float f32x4_t __attribute__((ext_vector_type(4)));

__device__ __forceinline__ void gload_lds16(const void* g, void* l) {
  __builtin_amdgcn_global_load_lds((const __attribute__((address_space(1))) void*)g,
                                   (__attribute__((address_space(3))) void*)l,
                                   16, 0, 0);
}

// K0: z<16: transpose (C,L)fp32 -> (L,C)fp16 for Q (z<8) / K (z>=8), 32l x 64c tiles.
//     z>=16: V fp32 -> fp16 elementwise (2 float4 per thread).
__global__ __launch_bounds__(256) void k_prep(const float* __restrict__ Q,
                                              const float* __restrict__ K,
                                              const float* __restrict__ V,
                                              _Float16* __restrict__ Qh,
                                              _Float16* __restrict__ Kh,
                                              _Float16* __restrict__ Vh) {
  const int z = blockIdx.z;
  if (z < 16) {
    __shared__ float tile[64][33];
    const float* src = (z < 8) ? Q : K;
    _Float16* dst = (z < 8) ? Qh : Kh;
    const int b = z & 7;
    const int l0 = blockIdx.x * 32, c0 = blockIdx.y * 64;
    const float* s = src + (size_t)b * C * L;
    const int tx = threadIdx.x, ty = threadIdx.y;
#pragma unroll
    for (int i = 0; i < 8; ++i)
      tile[ty + 8 * i][tx] = s[(size_t)(c0 + ty + 8 * i) * L + l0 + tx];
    __syncthreads();
    _Float16* d = dst + (size_t)b * L * C;
#pragma unroll
    for (int i = 0; i < 4; ++i) {
      int l = ty + 8 * i;
      f16x2 h2;
      h2[0] = (_Float16)tile[2 * tx][l];
      h2[1] = (_Float16)tile[2 * tx + 1][l];
      *(f16x2*)(d + (size_t)(l0 + l) * C + c0 + 2 * tx) = h2;
    }
  } else {
    int blk = ((z - 16) * 4 + blockIdx.y) * 64 + blockIdx.x;  // 0..2047
    int tid = blk * 256 + threadIdx.y * 32 + threadIdx.x;     // 0..524287
#pragma unroll
    for (int u = 0; u < 2; ++u) {
      int i = tid + u * 524288;
      float4 v = ((const float4*)V)[i];
      f16x4 o = { (_Float16)v.x, (_Float16)v.y, (_Float16)v.z, (_Float16)v.w };
      ((f16x4*)Vh)[i] = o;
    }
  }
}

// K1: QK^T GEMM (128x128 tile, BK=64, single-buffered, 33KB LDS, 4 blocks/CU)
//     -> exp -> fp16 att_h + rowsum partials. 1D grid, b fastest (XCD pin).
__global__ __launch_bounds__(256, 4) void k_energy_exp(const _Float16* __restrict__ Qh,
                                                       const _Float16* __restrict__ Kh,
                                                       _Float16* __restrict__ atth,
                                                       float* __restrict__ partials) {
  const int idx = blockIdx.x;
  const int b = idx & 7, li = (idx >> 3) & 15, mi = idx >> 7;
  if (mi >= li + 10) return;  // fully-masked tile: never read downstream
  const int m0 = mi * 128, l0 = li * 128;
  __shared__ char smem[33 * 1024];
  // A @0 (16KB), B @16K (16KB); Ph (32KB) aliases A+B; rp @32K (512B)
  const _Float16* Qb = Qh + (size_t)b * L * C;
  const _Float16* Kb = Kh + (size_t)b * L * C;
  const int t = threadIdx.x, lane = t & 63, wv = t >> 6;
  const int wr = (wv >> 1) * 64, wc = (wv & 1) * 64;
  const int fr = lane & 15, hi = lane >> 4;
  f32x4_t acc[4][4] = {};

  for (int s = 0; s < 4; ++s) {
    const int k0 = s * 64;
#pragma unroll
    for (int ss = 0; ss < 4; ++ss) {
      int q = ss * 256 + t;                 // 1024 chunks of 16B per matrix
      int row = q >> 3, seg = q & 7, g = seg ^ (row & 7);
      gload_lds16(Qb + (size_t)(l0 + row) * C + k0 + g * 8, smem + q * 16);
      gload_lds16(Kb + (size_t)(m0 + row) * C + k0 + g * 8, smem + 16384 + q * 16);
    }
    __syncthreads();                        // stage complete (vmcnt drained)
#pragma unroll
    for (int kk = 0; kk < 2; ++kk) {
      f16x8 ar[4], br[4];
      const int g = kk * 4 + hi;
#pragma unroll
      for (int i = 0; i < 4; ++i) {
        int r = wr + i * 16 + fr;
        ar[i] = *(const f16x8*)(smem + r * 128 + ((g ^ (r & 7)) * 16));
      }
#pragma unroll
      for (int j = 0; j < 4; ++j) {
        int r = wc + j * 16 + fr;
        br[j] = *(const f16x8*)(smem + 16384 + r * 128 + ((g ^ (r & 7)) * 16));
      }
#pragma unroll
      for (int i = 0; i < 4; ++i)
#pragma unroll
        for (int j = 0; j < 4; ++j)
          acc[i][j] = __builtin_amdgcn_mfma_f32_16x16x32_f16(ar[i], br[j], acc[i][j], 0, 0, 0);
    }
    __syncthreads();                        // WAR: reads done before next stage
  }
  // epilogue: exp (masked -> 1e-6), pack pairs, write swizzled Ph (aliases staging)
  char* Ph = smem;
  float* rp = (float*)(smem + 32768);
#pragma unroll
  for (int i = 0; i < 4; ++i)
#pragma unroll
    for (int j = 0; j < 4; ++j) {
      float ev[4];
#pragma unroll
      for (int r = 0; r < 4; ++r) {
        int gl = l0 + wr + i * 16 + hi * 4 + r;
        int gm = m0 + wc + j * 16 + fr;
        ev[r] = (gm <= gl + BAND) ? __expf(acc[i][j][r] * SCALE) : 1e-6f;
      }
#pragma unroll
      for (int r = 0; r < 4; ++r) {
        float p = __shfl_xor(ev[r], 1);
        if (!(fr & 1)) {
          int lrow = wr + i * 16 + hi * 4 + r;
          int mcol = wc + j * 16 + fr;
          f16x2 h2;
          h2[0] = (_Float16)ev[r];
          h2[1] = (_Float16)p;
          *(f16x2*)(Ph + lrow * 256 + ((mcol * 2) ^ ((lrow & 7) << 4))) = h2;
        }
      }
    }
  __syncthreads();
  // cooperative: Ph -> global att_h (coalesced 16B) + per-row sums
#pragma unroll
  for (int s = 0; s < 8; ++s) {
    int idx2 = t + 256 * s;
    int row = idx2 >> 4, ch = idx2 & 15;
    f16x8 v = *(const f16x8*)(Ph + row * 256 + ((ch * 16) ^ ((row & 7) << 4)));
    *(f16x8*)(atth + ((size_t)b * L + l0 + row) * L + m0 + ch * 8) = v;
    float sm = 0.f;
#pragma unroll
    for (int e = 0; e < 8; ++e) sm += (float)v[e];
    sm += __shfl_xor(sm, 1);
    sm += __shfl_xor(sm, 2);
    sm += __shfl_xor(sm, 4);
    sm += __shfl_xor(sm, 8);
    if ((t & 15) == 0) rp[row] = sm;
  }
  __syncthreads();
  if (t < 128) partials[((size_t)b * 16 + mi) * L + l0 + t] = rp[t];
}

// K2: per (b, 32-row l strip): inline rinv, then m-steps of 64, single-buffered
//     (36.5KB LDS, 4 blocks/CU = 32 waves): fp32 att write (rv*P) AND PV MFMA.
__global__ __launch_bounds__(512, 8) void k_fused(const _Float16* __restrict__ Vh,
                                                  const _Float16* __restrict__ atth,
                                                  const float* __restrict__ partials,
                                                  float* __restrict__ att,
                                                  float* __restrict__ out) {
  const int b = blockIdx.x & 7, li = blockIdx.x >> 3;  // b fastest: batch->XCD
  const int l0 = li * 32;
  const int nsteps = min(32, (l0 + 1120 + 63) >> 6);   // 64-col steps (band cover)
  __shared__ char smem[36 * 1024];   // V @0 (32KB: 256x64 fp16), P @32K (4KB)
  __shared__ float rinvS[32];
  const _Float16* Vb = Vh + (size_t)b * C * L;
  const _Float16* ab = atth + (size_t)b * L * L;
  float* attb = att + (size_t)b * L * L;
  float* outb = out + (size_t)b * C * L;
  const int t = threadIdx.x, lane = t & 63, wv = t >> 6;
  const int fr = lane & 15, hi = lane >> 4;
  const int cbase = wv * 32;

  // inline rinv: 16 threads per row, one partial each (or analytic for skipped)
  {
    int row = t >> 4, mi = t & 15;
    int l = l0 + row;
    int nsum = min(16, (l >> 7) + 10);
    float v = (mi < nsum) ? partials[((size_t)b * 16 + mi) * L + l] : 1.28e-4f;
    v += __shfl_xor(v, 1);
    v += __shfl_xor(v, 2);
    v += __shfl_xor(v, 4);
    v += __shfl_xor(v, 8);
    if (mi == 0) rinvS[row] = 1.f / v;
  }
  __syncthreads();
  const float rv_row = rinvS[t >> 4];
  float rvj[2];
#pragma unroll
  for (int j = 0; j < 2; ++j) rvj[j] = rinvS[j * 16 + fr];
  f32x4_t acc[2][2] = {};

  for (int s = 0; s < nsteps; ++s) {
    const int m0 = s * 64;
#pragma unroll
    for (int ss = 0; ss < 4; ++ss) {
      int q = ss * 512 + t;                  // V: 2048 chunks (256 rows x 128B)
      int row = q >> 3, seg = q & 7, g = seg ^ (row & 7);
      gload_lds16(Vb + (size_t)row * L + m0 + g * 8, smem + q * 16);
    }
    if (t < 256) {
      int q = t;                             // P: 256 chunks (32 rows x 128B)
      int row = q >> 3, seg = q & 7, g = seg ^ (row & 7);
      gload_lds16(ab + (size_t)(l0 + row) * L + m0 + g * 8, smem + 32768 + q * 16);
    }
    __syncthreads();                         // stage complete
    // normalized fp32 att write from P tile (16 threads/row, 16B each)
    {
      int row = t >> 4, ch = (t & 15) >> 1, half = t & 1;
      f16x4 h = *(const f16x4*)(smem + 32768 + row * 128 + ((ch ^ (row & 7)) * 16) + half * 8);
      float4 o = make_float4((float)h[0] * rv_row, (float)h[1] * rv_row,
                             (float)h[2] * rv_row, (float)h[3] * rv_row);
      *(float4*)(attb + (size_t)(l0 + row) * L + m0 + ch * 8 + half * 4) = o;
    }
    // PV MFMA: out[c,l] += V[c,m]*P[l,m]
#pragma unroll
    for (int kk = 0; kk < 2; ++kk) {
      f16x8 a_[2], b_[2];
      const int g = kk * 4 + hi;
#pragma unroll
      for (int i = 0; i < 2; ++i) {
        int r = cbase + i * 16 + fr;
        a_[i] = *(const f16x8*)(smem + r * 128 + ((g ^ (r & 7)) * 16));
      }
#pragma unroll
      for (int j = 0; j < 2; ++j) {
        int r = j * 16 + fr;
        b_[j] = *(const f16x8*)(smem + 32768 + r * 128 + ((g ^ (r & 7)) * 16));
      }
#pragma unroll
      for (int i = 0; i < 2; ++i)
#pragma unroll
        for (int j = 0; j < 2; ++j)
          acc[i][j] = __builtin_amdgcn_mfma_f32_16x16x32_f16(a_[i], b_[j], acc[i][j], 0, 0, 0);
    }
    __syncthreads();                         // WAR: reads done before next stage
  }
  // masked tail fill: cols [Mcov, 2048) = 1e-6 * rinv
  const int Mcov = nsteps * 64;
  if (Mcov < L) {
    const int row = t >> 4;
    const int npt = (L - Mcov) >> 6;  // float4s per thread (16 threads/row)
    const float cv = 1e-6f * rv_row;
    const float4 cst = make_float4(cv, cv, cv, cv);
    float* dst = attb + (size_t)(l0 + row) * L;
    for (int u = 0; u < npt; ++u) {
      int m = Mcov + ((t & 15) + u * 16) * 4;
      *(float4*)(dst + m) = cst;
    }
  }
  // out epilogue with rinv scale
#pragma unroll
  for (int i = 0; i < 2; ++i)
#pragma unroll
    for (int j = 0; j < 2; ++j)
#pragma unroll
      for (int r = 0; r < 4; ++r) {
        int c = cbase + i * 16 + hi * 4 + r;
        int l = j * 16 + fr;
        outb[(size_t)c * L + l0 + l] = acc[i][j][r] * rvj[j];
      }
}

extern "C" void kernel_launch(void* const* d_in, const int* in_sizes, int n_in,
                              void* d_out, int out_size, void* d_ws, size_t ws_size,
                              hipStream_t stream) {
  const float* Q = (const float*)d_in[0];
  const float* K = (const float*)d_in[1];
  const float* V = (const float*)d_in[2];
  float* out = (float*)d_out;
  float* att = out + (size_t)B * C * L;

  char* w = (char*)d_ws;
  const size_t szT = (size_t)B * L * C * 2;           // 8 MiB per fp16 tensor
  _Float16* Qh = (_Float16*)(w);
  _Float16* Kh = (_Float16*)(w + szT);
  _Float16* Vh = (_Float16*)(w + 2 * szT);
  _Float16* atth = (_Float16*)(w + 3 * szT);          // (B,L,L) fp16 = 64 MiB
  float* partials = (float*)(w + 3 * szT + (size_t)B * L * L * 2);

  k_prep<<<dim3(64, 4, 24), dim3(32, 8), 0, stream>>>(Q, K, V, Qh, Kh, Vh);
  k_energy_exp<<<2048, 256, 0, stream>>>(Qh, Kh, atth, partials);
  k_fused<<<512, 512, 0, stream>>>(Vh, atth, partials, att, out);
}